// Round 1
// baseline (847.280 us; speedup 1.0000x reference)
//
#include <hip/hip_runtime.h>
#include <hip/hip_fp16.h>

typedef _Float16 f16;
typedef _Float16 f16x8 __attribute__((ext_vector_type(8)));
typedef _Float16 f16x4 __attribute__((ext_vector_type(4)));
typedef float    f32x4 __attribute__((ext_vector_type(4)));

#define BS  2048
#define NE  64
#define NQ  16
#define DIM 512
#define NH  8
#define HD  64

// async global->LDS, 16B per lane. LDS dest must be wave-uniform base; HW adds lane*16.
__device__ __forceinline__ void gload16(const void* g, void* l) {
  __builtin_amdgcn_global_load_lds(
      (const __attribute__((address_space(1))) unsigned int*)g,
      (__attribute__((address_space(3))) unsigned int*)l, 16, 0, 0);
}

__global__ __launch_bounds__(256)
void cvt_kernel(const float* __restrict__ src, f16* __restrict__ dst, int n4) {
  int i  = blockIdx.x * blockDim.x + threadIdx.x;
  int st = gridDim.x * blockDim.x;
  for (; i < n4; i += st) {
    float4 v = reinterpret_cast<const float4*>(src)[i];
    f16x4 o;
    o[0] = (f16)v.x; o[1] = (f16)v.y; o[2] = (f16)v.z; o[3] = (f16)v.w;
    reinterpret_cast<f16x4*>(dst)[i] = o;
  }
}

// C = A (M x 512) * Bw^T (Bw: N x 512), 128x128 tile, 4 waves, 16x16x32 f16 MFMA.
// EPI 0: route qkv columns -> oQ (rows n%64<16), oK, oV (f16)
// EPI 1: out = acc + bias[col]; zero row if pmask[row]; f32 store
template<int EPI>
__global__ __launch_bounds__(256, 2)
void gemm128(const f16* __restrict__ A, const f16* __restrict__ Bw,
             f16* __restrict__ oQ, f16* __restrict__ oK, f16* __restrict__ oV,
             float* __restrict__ oF, const float* __restrict__ bias,
             const int* __restrict__ pmask)
{
  __shared__ alignas(16) f16 As[128 * 64];
  __shared__ alignas(16) f16 Bs[128 * 64];
  const int tid  = threadIdx.x;
  const int wave = tid >> 6;
  const int lane = tid & 63;
  const int brow = blockIdx.x * 128;
  const int bcol = blockIdx.y * 128;
  const int wr = (wave >> 1) * 64;   // wave row origin in tile
  const int wc = (wave & 1)  * 64;   // wave col origin in tile
  const int fr = lane & 15;          // fragment row/col index
  const int fq = lane >> 4;          // quad (k-chunk / acc row group)
  const int sr = tid >> 3;           // staging row 0..31
  const int sc = (tid & 7) << 3;     // staging col 0,8,..,56

  f32x4 acc[4][4];
#pragma unroll
  for (int m = 0; m < 4; ++m)
#pragma unroll
    for (int n = 0; n < 4; ++n)
      acc[m][n] = (f32x4){0.f, 0.f, 0.f, 0.f};

  const f16* Ag = A  + (size_t)(brow + sr) * 512 + sc;
  const f16* Bg = Bw + (size_t)(bcol + sr) * 512 + sc;
  f16* AsW = &As[wave * 512];  // wave-uniform LDS base
  f16* BsW = &Bs[wave * 512];

  for (int k0 = 0; k0 < 512; k0 += 64) {
#pragma unroll
    for (int i = 0; i < 4; ++i) {
      gload16(Ag + (size_t)(i * 32) * 512 + k0, AsW + i * 2048);
      gload16(Bg + (size_t)(i * 32) * 512 + k0, BsW + i * 2048);
    }
    __syncthreads();  // drains vmcnt before barrier
#pragma unroll
    for (int kk = 0; kk < 2; ++kk) {
      f16x8 af[4], bfr[4];
#pragma unroll
      for (int m = 0; m < 4; ++m)
        af[m] = *reinterpret_cast<const f16x8*>(&As[(wr + m * 16 + fr) * 64 + kk * 32 + fq * 8]);
#pragma unroll
      for (int n = 0; n < 4; ++n)
        bfr[n] = *reinterpret_cast<const f16x8*>(&Bs[(wc + n * 16 + fr) * 64 + kk * 32 + fq * 8]);
#pragma unroll
      for (int m = 0; m < 4; ++m)
#pragma unroll
        for (int n = 0; n < 4; ++n)
          acc[m][n] = __builtin_amdgcn_mfma_f32_16x16x32_f16(af[m], bfr[n], acc[m][n], 0, 0, 0);
    }
    __syncthreads();
  }

  // epilogue: D[row][col], row = fq*4 + r (within 16), col = fr
#pragma unroll
  for (int m = 0; m < 4; ++m) {
    const int grow0 = brow + wr + m * 16 + fq * 4;
#pragma unroll
    for (int n = 0; n < 4; ++n) {
      const int gcol = bcol + wc + n * 16 + fr;
#pragma unroll
      for (int r = 0; r < 4; ++r) {
        const int grow = grow0 + r;
        const float v = acc[m][n][r];
        if constexpr (EPI == 0) {
          if (gcol < 512) {
            const int e = grow & 63;
            if (e < 16) {
              const int qrow = (grow >> 6) * 16 + e;
              oQ[(size_t)qrow * 512 + gcol] = (f16)v;
            }
          } else if (gcol < 1024) {
            oK[(size_t)grow * 512 + (gcol - 512)] = (f16)v;
          } else {
            oV[(size_t)grow * 512 + (gcol - 1024)] = (f16)v;
          }
        } else {
          float o = v + bias[gcol];
          if (pmask[grow] != 0) o = 0.f;
          oF[(size_t)grow * 512 + gcol] = o;
        }
      }
    }
  }
}

// one block per (batch, head): QK^T -> masked softmax -> PV, all f32 accumulate
__global__ __launch_bounds__(256)
void attn_kernel(const f16* __restrict__ Q, const f16* __restrict__ K,
                 const f16* __restrict__ V, const int* __restrict__ pre_mask,
                 f16* __restrict__ AO)
{
  const int b = blockIdx.x;
  const int h = blockIdx.y;
  __shared__ alignas(16) f16 Qs[16 * 64];
  __shared__ alignas(16) f16 Ks[64 * 72];  // +8 pad: break 512B-stride bank conflict
  __shared__ alignas(16) f16 Vs[64 * 72];
  __shared__ float Ps[16 * 64];
  const int tid = threadIdx.x;

  if (tid < 128) {
    const int row = tid >> 3, col = (tid & 7) << 3;
    *reinterpret_cast<f16x8*>(&Qs[row * 64 + col]) =
        *reinterpret_cast<const f16x8*>(&Q[((size_t)b * 16 + row) * 512 + h * 64 + col]);
  }
#pragma unroll
  for (int i = 0; i < 2; ++i) {
    const int idx = i * 256 + tid;  // 0..511 -> 8 f16 each
    const int row = idx >> 3, col = (idx & 7) << 3;
    *reinterpret_cast<f16x8*>(&Ks[row * 72 + col]) =
        *reinterpret_cast<const f16x8*>(&K[((size_t)b * 64 + row) * 512 + h * 64 + col]);
    *reinterpret_cast<f16x8*>(&Vs[row * 72 + col]) =
        *reinterpret_cast<const f16x8*>(&V[((size_t)b * 64 + row) * 512 + h * 64 + col]);
  }
  __syncthreads();

  const int q  = tid >> 4;          // 0..15
  const int e0 = (tid & 15) << 2;   // 0,4,..,60
  float lg[4];
#pragma unroll
  for (int j = 0; j < 4; ++j) {
    const int e = e0 + j;
    float dot = 0.f;
#pragma unroll
    for (int d = 0; d < 64; d += 8) {
      f16x8 qv = *reinterpret_cast<const f16x8*>(&Qs[q * 64 + d]);
      f16x8 kv = *reinterpret_cast<const f16x8*>(&Ks[e * 72 + d]);
#pragma unroll
      for (int x = 0; x < 8; ++x) dot += (float)qv[x] * (float)kv[x];
    }
    const int pm = pre_mask[((size_t)b * 64 + q) * 64 + e];
    lg[j] = pm ? -__builtin_inff() : dot * 0.125f;
  }
  // row softmax across the 16 lanes owning this q-row (consecutive lanes)
  float mx = fmaxf(fmaxf(lg[0], lg[1]), fmaxf(lg[2], lg[3]));
#pragma unroll
  for (int s = 1; s < 16; s <<= 1) mx = fmaxf(mx, __shfl_xor(mx, s, 64));
  float p[4], sum = 0.f;
#pragma unroll
  for (int j = 0; j < 4; ++j) {
    p[j] = (lg[j] == -__builtin_inff()) ? 0.f : __expf(lg[j] - mx);
    sum += p[j];
  }
#pragma unroll
  for (int s = 1; s < 16; s <<= 1) sum += __shfl_xor(sum, s, 64);
  const float inv = sum > 0.f ? 1.f / sum : 0.f;  // all-masked row -> 0 (matches NaN->0)
#pragma unroll
  for (int j = 0; j < 4; ++j) Ps[q * 64 + e0 + j] = p[j] * inv;
  __syncthreads();

  const int hd0 = e0;
  float a0 = 0.f, a1 = 0.f, a2 = 0.f, a3 = 0.f;
#pragma unroll 8
  for (int e = 0; e < 64; ++e) {
    const float a = Ps[q * 64 + e];
    f16x4 v = *reinterpret_cast<const f16x4*>(&Vs[e * 72 + hd0]);
    a0 += a * (float)v[0];
    a1 += a * (float)v[1];
    a2 += a * (float)v[2];
    a3 += a * (float)v[3];
  }
  f16x4 ov;
  ov[0] = (f16)a0; ov[1] = (f16)a1; ov[2] = (f16)a2; ov[3] = (f16)a3;
  *reinterpret_cast<f16x4*>(&AO[((size_t)b * 16 + q) * 512 + h * 64 + hd0]) = ov;
}

extern "C" void kernel_launch(void* const* d_in, const int* in_sizes, int n_in,
                              void* d_out, int out_size, void* d_ws, size_t ws_size,
                              hipStream_t stream) {
  const float* ent       = (const float*)d_in[0];
  const int*   pre_mask  = (const int*)d_in[1];
  const int*   post_mask = (const int*)d_in[2];
  const float* W_in      = (const float*)d_in[3];
  const float* W_out     = (const float*)d_in[4];
  const float* b_out     = (const float*)d_in[5];
  float* out = (float*)d_out;

  char* ws = (char*)d_ws;
  // workspace layout (bytes)
  f16* entH  = (f16*)(ws);                         // 2048*64*512*2  = 134217728
  f16* winH  = (f16*)(ws + 134217728);             // 1536*512*2    = 1572864
  f16* woutH = (f16*)(ws + 135790592);             // 512*512*2     = 524288
  f16* qH    = (f16*)(ws + 136314880);             // 32768*512*2   = 33554432
  f16* kH    = (f16*)(ws + 169869312);             // 131072*512*2  = 134217728
  f16* vH    = (f16*)(ws + 304087040);             // 131072*512*2  = 134217728
  f16* aoH   = (f16*)(ws);                         // reuse entH region after GEMM1 (33554432)
  // peak usage: 438304768 bytes

  cvt_kernel<<<2048, 256, 0, stream>>>(ent, entH, (BS * NE * DIM) / 4);
  cvt_kernel<<<768, 256, 0, stream>>>(W_in, winH, (3 * DIM * DIM) / 4);
  cvt_kernel<<<256, 256, 0, stream>>>(W_out, woutH, (DIM * DIM) / 4);

  gemm128<0><<<dim3((BS * NE) / 128, (3 * DIM) / 128), 256, 0, stream>>>(
      entH, winH, qH, kH, vH, nullptr, nullptr, nullptr);

  attn_kernel<<<dim3(BS, NH), 256, 0, stream>>>(qH, kH, vH, pre_mask, aoH);

  gemm128<1><<<dim3((BS * NQ) / 128, DIM / 128), 256, 0, stream>>>(
      aoH, woutH, nullptr, nullptr, nullptr, out, b_out, post_mask);
}